// Round 18
// baseline (76.022 us; speedup 1.0000x reference)
//
#include <hip/hip_runtime.h>
#include <math.h>

#define BLK 1024         // threads per block (16 waves)
#define NBLK 256         // blocks = M/GSZ (1 per CU)
#define GSZ 32           // checkpoints per block
#define HSZ 8            // checkpoints per group (4 waves per group)
#define NW 16            // waves per block
#define SEGW 256         // k-elements per moment segment
#define SEGSH 8          // log2(SEGW)
#define NSEG_NEAR 3      // far/near boundary: 3*256 = 768 steps exact
#define NDEG 6           // expansion degree (moments 0..6)
#define LSTRIDE 9        // LDS floats per segment record (odd: conflict-free)
#define MAXSEG 64        // 16384/256
#define LSTG 2048        // staged near-field elements
#define GRPBLK 16        // blocks per atomic group
#define NREP 4           // diagnostic: 4x body replication (rep 0 = real)
#define SCALEF 1.125899906842624e15f   // 2^50 fixed-point scale
#define INV_SCALE (1.0 / 1.125899906842624e15)

#if __has_builtin(__builtin_amdgcn_rsqf)
#define RSQF(x) __builtin_amdgcn_rsqf(x)
#else
#define RSQF(x) (1.0f / sqrtf(x))
#endif
#if __has_builtin(__builtin_amdgcn_rcpf)
#define RCPF(x) __builtin_amdgcn_rcpf(x)
#else
#define RCPF(x) (1.0f / (x))
#endif

__device__ __forceinline__ float fast_pow(float x, float e) {
  return __expf(e * __logf(x));
}

__device__ __forceinline__ float bsum64(float v) {
#pragma unroll
  for (int m = 1; m < 64; m <<= 1) v += __shfl_xor(v, m, 64);
  return v;
}

// Atomic tree slots, each on its OWN 128B line (R15/R16 lesson).
struct __align__(128) Slot { long long acc; unsigned cnt; };
__device__ Slot g_grp[NBLK / GRPBLK];
__device__ Slot g_root;

// ---------------------------------------------------------------------------
// One full compute pass (prep + stage + far + near). real=false: sink acc,
// skip epilogue (diagnostic replication, rule-17 DCE-safe). Cr/gam_r are
// per-rep perturbed so NOTHING downstream is CSE/hoistable across reps.
// ---------------------------------------------------------------------------
template <bool USE_RSQ>
__device__ __forceinline__ void body(
    const float* __restrict__ S1, const int* __restrict__ step,
    const float* __restrict__ loss, const float* __restrict__ lrs,
    const float* __restrict__ lr_sum, const float* __restrict__ lr_gap,
    const float* __restrict__ L0_p, const float* __restrict__ A_p,
    const float* __restrict__ alpha_p, const float* __restrict__ B_p,
    float Cr, float nb, float* __restrict__ out, int T,
    float (&segm)[MAXSEG][LSTRIDE], float (&lc)[LSTG], float (&ldd)[LSTG],
    float (&lgp)[LSTG], float (&wacc)[NW][GSZ], float gam_r, bool real) {
  int tid = threadIdx.x, bid = blockIdx.x;
  int lane = tid & 63, wid = tid >> 6;
  int grp = tid >> 8;
  int jb = grp * HSZ;
  int htid = tid & 255;

  int mbase = bid * GSZ;

  // ---- block-wide scan ----
  int nsegmax = 0, minlo = 1 << 30, utop = 0;
#pragma unroll
  for (int jj = 0; jj < GSZ; ++jj) {
    int s = step[mbase + jj];
    int ks = max(0, (s >> SEGSH) - NSEG_NEAR);
    nsegmax = max(nsegmax, ks);
    minlo = min(minlo, ks << SEGSH);
    utop = max(utop, s);
  }
  int ubase = minlo;
  int ucnt = min(LSTG, (utop - ubase + 7) & ~3);

  // ---- prep: per-wave segment moments ----
  for (int seg = wid; seg < nsegmax; seg += NW) {
    float dk[4], wk[4];
#pragma unroll
    for (int e = 0; e < 4; ++e) {
      int k = seg * SEGW + lane * 4 + e;
      if (k == 0) {
        dk[e] = 0.0f; wk[e] = 0.0f;
      } else {
        float lg = __logf(lrs[k]);
        float c  = Cr * __expf(-gam_r * lg);
        dk[e] = RCPF(c) - lr_sum[k - 1];
        wk[e] = USE_RSQ ? (lr_gap[k] * RSQF(c))
                        : (lr_gap[k] * fast_pow(c, nb));
      }
    }
    float d0 = bsum64(dk[0] + dk[1] + dk[2] + dk[3]) * (1.0f / 256.0f);
    float e0 = dk[0] - d0, e1 = dk[1] - d0, e2 = dk[2] - d0, e3 = dk[3] - d0;
    float p0 = wk[0], p1 = wk[1], p2 = wk[2], p3 = wk[3];
    float b = 1.0f;
#pragma unroll
    for (int n = 0; n <= NDEG; ++n) {
      float v = bsum64(p0 + p1 + p2 + p3);
      if (lane == 0) segm[seg][1 + n] = b * v;
      p0 *= e0; p1 *= e1; p2 *= e2; p3 *= e3;
      b *= (nb - (float)n) / (float)(n + 1);
    }
    if (lane == 0) segm[seg][0] = d0;
  }

  // ---- stage near-field (c, dd, g) into LDS ----
  for (int i = tid; i < ucnt; i += BLK) {
    int k = ubase + i;
    if (k == 0 || k >= T) {
      lc[i] = 0.0f; ldd[i] = 1.0f; lgp[i] = 0.0f;
    } else {
      float lg = __logf(lrs[k]);
      float c  = Cr * __expf(-gam_r * lg);
      lc[i] = c;
      ldd[i] = fmaf(-c, lr_sum[k - 1], 1.0f);
      lgp[i] = lr_gap[k];
    }
  }
  __syncthreads();

  // ---- per-group checkpoint state ----
  float Ss[HSZ], acc[HSZ]; int sv[HSZ], ksg[HSZ];
  int lo_g = 1 << 30, smax_g = 0, nsegh = 0;
#pragma unroll
  for (int jj = 0; jj < HSZ; ++jj) {
    int m = mbase + jb + jj;
    Ss[jj] = S1[m];
    int s = step[m];
    sv[jj] = s;
    int kg = max(0, (s >> SEGSH) - NSEG_NEAR);
    ksg[jj] = kg;
    acc[jj] = 0.0f;
    lo_g = min(lo_g, kg << SEGSH);
    smax_g = max(smax_g, s);
    nsegh = max(nsegh, kg);
  }

  // ---- far field ----
  if (htid < nsegh) {
    float d0 = segm[htid][0];
    float mm[NDEG + 1];
#pragma unroll
    for (int n = 0; n <= NDEG; ++n) mm[n] = segm[htid][1 + n];
#pragma unroll
    for (int jj = 0; jj < HSZ; ++jj) {
      float s_ = Ss[jj] + d0;
      float r = RCPF(s_);
      float tb = USE_RSQ ? RSQF(s_) : fast_pow(s_, nb);
      float h = mm[NDEG];
#pragma unroll
      for (int n = NDEG - 1; n >= 0; --n) h = fmaf(h, r, mm[n]);
      float contrib = tb * h;
      acc[jj] += (htid < ksg[jj]) ? contrib : 0.0f;
    }
  }

  // ---- near field: masked sweep from staged LDS ----
  for (int kb = lo_g + htid * 4; kb <= smax_g; kb += 256 * 4) {
    int idx = kb - ubase;
    float ce[4], de[4], ge[4];
    if (idx < LSTG) {
      float4 c4 = *(const float4*)&lc[idx];
      float4 d4 = *(const float4*)&ldd[idx];
      float4 g4 = *(const float4*)&lgp[idx];
      ce[0]=c4.x; ce[1]=c4.y; ce[2]=c4.z; ce[3]=c4.w;
      de[0]=d4.x; de[1]=d4.y; de[2]=d4.z; de[3]=d4.w;
      ge[0]=g4.x; ge[1]=g4.y; ge[2]=g4.z; ge[3]=g4.w;
    } else {
#pragma unroll
      for (int e = 0; e < 4; ++e) {
        int k = kb + e;
        if (k < 1 || k >= T) { ce[e]=0.0f; de[e]=1.0f; ge[e]=0.0f; }
        else {
          float lg = __logf(lrs[k]);
          float c  = Cr * __expf(-gam_r * lg);
          ce[e] = c; de[e] = fmaf(-c, lr_sum[k - 1], 1.0f); ge[e] = lr_gap[k];
        }
      }
    }
#pragma unroll
    for (int e = 0; e < 4; ++e) {
#pragma unroll
      for (int jj = 0; jj < HSZ; ++jj) {
        float inner = fmaf(ce[e], Ss[jj], de[e]);
        float p = USE_RSQ ? RSQF(inner) : __expf(nb * __logf(inner));
        unsigned off = (unsigned)(kb + e - (ksg[jj] << SEGSH));
        unsigned rngj = (unsigned)(sv[jj] - (ksg[jj] << SEGSH));
        float pm = (off <= rngj) ? p : 0.0f;
        acc[jj] = fmaf(ge[e], pm, acc[jj]);
      }
    }
  }

  if (!real) {  // diagnostic rep: keep compute alive, free LDS for next rep
#pragma unroll
    for (int jj = 0; jj < HSZ; ++jj) asm volatile("" : : "v"(acc[jj]));
    __syncthreads();
    return;
  }

  // ---- block reduce ----
#pragma unroll
  for (int jj = 0; jj < HSZ; ++jj) {
    float v = acc[jj];
#pragma unroll
    for (int off = 32; off; off >>= 1) v += __shfl_down(v, off, 64);
    if (lane == 0) wacc[wid][jb + jj] = v;
  }
  __syncthreads();

  // ---- epilogue + tree-reduced deterministic global sum ----
  long long ll = 0;
  if (tid < GSZ) {
    int j = tid;
    int m = mbase + j;
    int w0 = (j >> 3) * 4;
    float sgp = wacc[w0][j] + wacc[w0 + 1][j] + wacc[w0 + 2][j] + wacc[w0 + 3][j];
    int s = step[m];
    float Ssum = S1[m];
    float LD = (lrs[0] - lrs[s]) - sgp;
    float pred = L0_p[0] + A_p[0] * fast_pow(Ssum, -alpha_p[0]) + B_p[0] * LD;
    pred = fmaxf(pred, 1e-10f);
    float r = __logf(loss[m]) - __logf(pred);
    float a = fabsf(r);
    const float dlt = 0.001f;
    float hubv = (a <= dlt) ? (0.5f * r * r) : (dlt * (a - 0.5f * dlt));
    ll = (long long)(hubv * SCALEF + 0.5f);
  }
  if (wid == 0) {
#pragma unroll
    for (int off = 16; off; off >>= 1) ll += __shfl_down(ll, off, 64);
    if (lane == 0) {
      int gi = bid / GRPBLK;
      __hip_atomic_fetch_add(&g_grp[gi].acc, ll, __ATOMIC_RELAXED,
                             __HIP_MEMORY_SCOPE_AGENT);
      unsigned old = __hip_atomic_fetch_add(&g_grp[gi].cnt, 1u,
                                            __ATOMIC_ACQ_REL,
                                            __HIP_MEMORY_SCOPE_AGENT);
      if (old == GRPBLK - 1) {
        long long gsum = __hip_atomic_load(&g_grp[gi].acc, __ATOMIC_RELAXED,
                                           __HIP_MEMORY_SCOPE_AGENT);
        __hip_atomic_store(&g_grp[gi].acc, 0ll, __ATOMIC_RELAXED,
                           __HIP_MEMORY_SCOPE_AGENT);
        __hip_atomic_store(&g_grp[gi].cnt, 0u, __ATOMIC_RELAXED,
                           __HIP_MEMORY_SCOPE_AGENT);
        __hip_atomic_fetch_add(&g_root.acc, gsum, __ATOMIC_RELAXED,
                               __HIP_MEMORY_SCOPE_AGENT);
        unsigned old2 = __hip_atomic_fetch_add(&g_root.cnt, 1u,
                                               __ATOMIC_ACQ_REL,
                                               __HIP_MEMORY_SCOPE_AGENT);
        if (old2 == (NBLK / GRPBLK) - 1) {
          long long tot = __hip_atomic_load(&g_root.acc, __ATOMIC_RELAXED,
                                            __HIP_MEMORY_SCOPE_AGENT);
          out[0] = (float)((double)tot * INV_SCALE);
          __hip_atomic_store(&g_root.acc, 0ll, __ATOMIC_RELAXED,
                             __HIP_MEMORY_SCOPE_AGENT);
          __hip_atomic_store(&g_root.cnt, 0u, __ATOMIC_RELAXED,
                             __HIP_MEMORY_SCOPE_AGENT);
        }
      }
    }
  }
}

__global__ __launch_bounds__(BLK) void fused_kernel(
    const float* __restrict__ S1, const int* __restrict__ step,
    const float* __restrict__ loss, const float* __restrict__ lrs,
    const float* __restrict__ lr_sum, const float* __restrict__ lr_gap,
    const float* __restrict__ L0_p, const float* __restrict__ A_p,
    const float* __restrict__ alpha_p, const float* __restrict__ B_p,
    const float* __restrict__ C_p, const float* __restrict__ beta_p,
    const float* __restrict__ gamma_p,
    float* __restrict__ out, int T) {
  __shared__ float segm[MAXSEG][LSTRIDE];
  __shared__ __align__(16) float lc[LSTG];
  __shared__ __align__(16) float ldd[LSTG];
  __shared__ __align__(16) float lgp[LSTG];
  __shared__ float wacc[NW][GSZ];

  float beta = beta_p[0];
  float C = C_p[0], gam = gamma_p[0];

  // Diagnostic: NREP passes; rep>0 perturbed+sunk, rep 0 (exact) is real
  // and runs LAST. #pragma unroll 1: code size flat (icache not inflated).
#pragma unroll 1
  for (int rep = NREP - 1; rep >= 0; --rep) {
    float eps = (float)rep * 5.9604645e-8f;   // r * 2^-24
    float Cr = C * (1.0f + eps);
    float gr = gam * (1.0f + eps);
    if (beta == 0.5f)
      body<true>(S1, step, loss, lrs, lr_sum, lr_gap, L0_p, A_p, alpha_p,
                 B_p, Cr, -0.5f, out, T, segm, lc, ldd, lgp, wacc, gr,
                 rep == 0);
    else
      body<false>(S1, step, loss, lrs, lr_sum, lr_gap, L0_p, A_p, alpha_p,
                  B_p, Cr, -beta, out, T, segm, lc, ldd, lgp, wacc, gr,
                  rep == 0);
  }
}

extern "C" void kernel_launch(void* const* d_in, const int* in_sizes, int n_in,
                              void* d_out, int out_size, void* d_ws, size_t ws_size,
                              hipStream_t stream) {
  const float* S1      = (const float*)d_in[0];
  const float* lrs     = (const float*)d_in[1];
  const float* lr_sum  = (const float*)d_in[2];
  const int*   step    = (const int*)  d_in[3];
  const float* lr_gap  = (const float*)d_in[4];
  const float* loss    = (const float*)d_in[5];
  const float* L0_p    = (const float*)d_in[6];
  const float* A_p     = (const float*)d_in[7];
  const float* alpha_p = (const float*)d_in[8];
  const float* B_p     = (const float*)d_in[9];
  const float* C_p     = (const float*)d_in[10];
  const float* beta_p  = (const float*)d_in[11];
  const float* gamma_p = (const float*)d_in[12];

  int M = in_sizes[0];
  int T = in_sizes[1];

  fused_kernel<<<M / GSZ, BLK, 0, stream>>>(
      S1, step, loss, lrs, lr_sum, lr_gap,
      L0_p, A_p, alpha_p, B_p, C_p, beta_p, gamma_p,
      (float*)d_out, T);
}

// Round 19
// 30.406 us; speedup vs baseline: 2.5002x; 2.5002x over previous
//
#include <hip/hip_runtime.h>
#include <math.h>

#define BLK 512          // threads per block (8 waves) — VGPR cap 256, NO spill
#define NBLK 256         // blocks = M/GSZ (1 per CU)
#define GSZ 32           // checkpoints per block
#define HSZ 8            // checkpoints per group
#define GTH 128          // threads per group (2 waves)
#define NW 8             // waves per block
#define SEGW 256         // k-elements per moment segment
#define SEGSH 8          // log2(SEGW)
#define NSEG_NEAR 3      // far/near boundary: 3*256 = 768 steps exact
#define NDEG 6           // expansion degree (moments 0..6)
#define LSTRIDE 9        // LDS floats per segment record (odd: conflict-free)
#define MAXSEG 64        // 16384/256
#define LSTG 2048        // staged near-field elements
#define GRPBLK 16        // blocks per atomic group
#define SCALEF 1.125899906842624e15f   // 2^50 fixed-point scale
#define INV_SCALE (1.0 / 1.125899906842624e15)

#if __has_builtin(__builtin_amdgcn_rsqf)
#define RSQF(x) __builtin_amdgcn_rsqf(x)
#else
#define RSQF(x) (1.0f / sqrtf(x))
#endif
#if __has_builtin(__builtin_amdgcn_rcpf)
#define RCPF(x) __builtin_amdgcn_rcpf(x)
#else
#define RCPF(x) (1.0f / (x))
#endif

__device__ __forceinline__ float fast_pow(float x, float e) {
  return __expf(e * __logf(x));  // x>0; ~1e-6 rel err vs 0.176 abs budget
}

__device__ __forceinline__ float bsum64(float v) {
#pragma unroll
  for (int m = 1; m < 64; m <<= 1) v += __shfl_xor(v, m, 64);
  return v;
}

// Atomic tree slots, each on its OWN 128B line (R15/R16 lesson).
// Zero-init at load; last users reset -> clean for every replay (proven
// across R15-R18 replays).
struct __align__(128) Slot { long long acc; unsigned cnt; };
__device__ Slot g_grp[NBLK / GRPBLK];
__device__ Slot g_root;

// ---------------------------------------------------------------------------
// R17 math at 512 threads (R18 diagnosis: launch_bounds(1024) caps VGPR at
// 64 -> ~196 B/thread scratch spill -> 650 GB/s scratch-bound, 5-6x slowdown.
// At 512 threads the cap is 256: the ~100-reg working set stays in registers).
// ---------------------------------------------------------------------------
template <bool USE_RSQ>
__device__ __forceinline__ void body(
    const float* __restrict__ S1, const int* __restrict__ step,
    const float* __restrict__ loss, const float* __restrict__ lrs,
    const float* __restrict__ lr_sum, const float* __restrict__ lr_gap,
    const float* __restrict__ L0_p, const float* __restrict__ A_p,
    const float* __restrict__ alpha_p, const float* __restrict__ B_p,
    float C, float nb, float* __restrict__ out, int T,
    float (&segm)[MAXSEG][LSTRIDE], float (&lc)[LSTG], float (&ldd)[LSTG],
    float (&lgp)[LSTG], float (&wacc)[NW][GSZ], float gam) {
  int tid = threadIdx.x, bid = blockIdx.x;
  int lane = tid & 63, wid = tid >> 6;
  int grp = tid >> 7;          // 4 groups x 2 waves
  int jb = grp * HSZ;
  int htid = tid & (GTH - 1);  // 0..127 within group

  int mbase = bid * GSZ;

  // ---- block-wide scan (broadcast loads) ----
  int nsegmax = 0, minlo = 1 << 30, utop = 0;
#pragma unroll
  for (int jj = 0; jj < GSZ; ++jj) {
    int s = step[mbase + jj];
    int ks = max(0, (s >> SEGSH) - NSEG_NEAR);
    nsegmax = max(nsegmax, ks);
    minlo = min(minlo, ks << SEGSH);
    utop = max(utop, s);
  }
  int ubase = minlo;
  int ucnt = min(LSTG, (utop - ubase + 7) & ~3);

  // ---- prep: per-wave segment moments (4 k's per lane, unrolled ILP) ----
  for (int seg = wid; seg < nsegmax; seg += NW) {
    float dk[4], wk[4];
#pragma unroll
    for (int e = 0; e < 4; ++e) {
      int k = seg * SEGW + lane * 4 + e;   // <= 60*256+255 < T always
      if (k == 0) {
        dk[e] = 0.0f; wk[e] = 0.0f;        // k=0 contributes nothing
      } else {
        float lg = __logf(lrs[k]);
        float c  = C * __expf(-gam * lg);  // C * lrs^-gamma
        dk[e] = RCPF(c) - lr_sum[k - 1];
        wk[e] = USE_RSQ ? (lr_gap[k] * RSQF(c))
                        : (lr_gap[k] * fast_pow(c, nb));
      }
    }
    float d0 = bsum64(dk[0] + dk[1] + dk[2] + dk[3]) * (1.0f / 256.0f);
    float e0 = dk[0] - d0, e1 = dk[1] - d0, e2 = dk[2] - d0, e3 = dk[3] - d0;
    float p0 = wk[0], p1 = wk[1], p2 = wk[2], p3 = wk[3];
    float b = 1.0f;                        // binom(nb, n) recurrence
#pragma unroll
    for (int n = 0; n <= NDEG; ++n) {      // unrolled: 7 bsum chains overlap
      float v = bsum64(p0 + p1 + p2 + p3);
      if (lane == 0) segm[seg][1 + n] = b * v;
      p0 *= e0; p1 *= e1; p2 *= e2; p3 *= e3;
      b *= (nb - (float)n) / (float)(n + 1);
    }
    if (lane == 0) segm[seg][0] = d0;
  }

  // ---- stage near-field (c, dd, g) once per block into LDS ----
  for (int i = tid; i < ucnt; i += BLK) {
    int k = ubase + i;
    if (k == 0 || k >= T) {
      lc[i] = 0.0f; ldd[i] = 1.0f; lgp[i] = 0.0f;
    } else {
      float lg = __logf(lrs[k]);
      float c  = C * __expf(-gam * lg);
      lc[i] = c;
      ldd[i] = fmaf(-c, lr_sum[k - 1], 1.0f);
      lgp[i] = lr_gap[k];
    }
  }
  __syncthreads();

  // ---- per-group checkpoint state (8-wide arrays) ----
  float Ss[HSZ], acc[HSZ]; int sv[HSZ], ksg[HSZ];
  int lo_g = 1 << 30, smax_g = 0, nsegh = 0;
#pragma unroll
  for (int jj = 0; jj < HSZ; ++jj) {
    int m = mbase + jb + jj;
    Ss[jj] = S1[m];
    int s = step[m];
    sv[jj] = s;
    int kg = max(0, (s >> SEGSH) - NSEG_NEAR);
    ksg[jj] = kg;
    acc[jj] = 0.0f;
    lo_g = min(lo_g, kg << SEGSH);
    smax_g = max(smax_g, s);
    nsegh = max(nsegh, kg);
  }

  // ---- far field: thread htid evaluates segment htid (nsegh <= 60 < 128) ----
  if (htid < nsegh) {
    float d0 = segm[htid][0];
    float mm[NDEG + 1];
#pragma unroll
    for (int n = 0; n <= NDEG; ++n) mm[n] = segm[htid][1 + n];
#pragma unroll
    for (int jj = 0; jj < HSZ; ++jj) {
      float s_ = Ss[jj] + d0;
      float r = RCPF(s_);
      float tb = USE_RSQ ? RSQF(s_) : fast_pow(s_, nb);
      float h = mm[NDEG];
#pragma unroll
      for (int n = NDEG - 1; n >= 0; --n) h = fmaf(h, r, mm[n]);
      float contrib = tb * h;
      acc[jj] += (htid < ksg[jj]) ? contrib : 0.0f;  // select AFTER compute
    }
  }

  // ---- near field: masked sweep from staged LDS (float4 inline) ----
  for (int kb = lo_g + htid * 4; kb <= smax_g; kb += GTH * 4) {
    int idx = kb - ubase;  // multiple of 4 (256-aligned bases)
    float4 c4, d4, g4;
    if (idx < LSTG) {
      c4 = *(const float4*)&lc[idx];
      d4 = *(const float4*)&ldd[idx];
      g4 = *(const float4*)&lgp[idx];
    } else {  // rare fallback: span exceeded LSTG — recompute
      float ce[4], de[4], ge[4];
#pragma unroll
      for (int e = 0; e < 4; ++e) {
        int k = kb + e;
        if (k < 1 || k >= T) { ce[e]=0.0f; de[e]=1.0f; ge[e]=0.0f; }
        else {
          float lg = __logf(lrs[k]);
          float c  = C * __expf(-gam * lg);
          ce[e] = c; de[e] = fmaf(-c, lr_sum[k - 1], 1.0f); ge[e] = lr_gap[k];
        }
      }
      c4 = {ce[0], ce[1], ce[2], ce[3]};
      d4 = {de[0], de[1], de[2], de[3]};
      g4 = {ge[0], ge[1], ge[2], ge[3]};
    }
    const float ce[4] = {c4.x, c4.y, c4.z, c4.w};
    const float de[4] = {d4.x, d4.y, d4.z, d4.w};
    const float ge[4] = {g4.x, g4.y, g4.z, g4.w};
#pragma unroll
    for (int e = 0; e < 4; ++e) {
#pragma unroll
      for (int jj = 0; jj < HSZ; ++jj) {
        float inner = fmaf(ce[e], Ss[jj], de[e]);  // may be <=0 if masked
        float p = USE_RSQ ? RSQF(inner) : __expf(nb * __logf(inner));
        unsigned off = (unsigned)(kb + e - (ksg[jj] << SEGSH));
        unsigned rngj = (unsigned)(sv[jj] - (ksg[jj] << SEGSH));
        float pm = (off <= rngj) ? p : 0.0f;  // select AFTER p (NaN-safe)
        acc[jj] = fmaf(ge[e], pm, acc[jj]);
      }
    }
  }

  // ---- block reduce: wave shuffle, then across the 2 group-waves via LDS ----
#pragma unroll
  for (int jj = 0; jj < HSZ; ++jj) {
    float v = acc[jj];
#pragma unroll
    for (int off = 32; off; off >>= 1) v += __shfl_down(v, off, 64);
    if (lane == 0) wacc[wid][jb + jj] = v;
  }
  __syncthreads();

  // ---- epilogue + tree-reduced deterministic global sum (R16, proven) ----
  long long ll = 0;
  if (tid < GSZ) {
    int j = tid;
    int m = mbase + j;
    int w0 = (j >> 3) * 2;   // 2 waves per group
    float sgp = wacc[w0][j] + wacc[w0 + 1][j];
    int s = step[m];
    float Ssum = S1[m];
    float LD = (lrs[0] - lrs[s]) - sgp;   // telescoped gap sum
    float pred = L0_p[0] + A_p[0] * fast_pow(Ssum, -alpha_p[0]) + B_p[0] * LD;
    pred = fmaxf(pred, 1e-10f);
    float r = __logf(loss[m]) - __logf(pred);
    float a = fabsf(r);
    const float dlt = 0.001f;
    float hubv = (a <= dlt) ? (0.5f * r * r) : (dlt * (a - 0.5f * dlt));
    ll = (long long)(hubv * SCALEF + 0.5f);  // hubv >= 0
  }
  if (wid == 0) {
#pragma unroll
    for (int off = 16; off; off >>= 1) ll += __shfl_down(ll, off, 64);
    if (lane == 0) {
      int gi = bid / GRPBLK;
      __hip_atomic_fetch_add(&g_grp[gi].acc, ll, __ATOMIC_RELAXED,
                             __HIP_MEMORY_SCOPE_AGENT);
      unsigned old = __hip_atomic_fetch_add(&g_grp[gi].cnt, 1u,
                                            __ATOMIC_ACQ_REL,
                                            __HIP_MEMORY_SCOPE_AGENT);
      if (old == GRPBLK - 1) {
        long long gsum = __hip_atomic_load(&g_grp[gi].acc, __ATOMIC_RELAXED,
                                           __HIP_MEMORY_SCOPE_AGENT);
        __hip_atomic_store(&g_grp[gi].acc, 0ll, __ATOMIC_RELAXED,
                           __HIP_MEMORY_SCOPE_AGENT);
        __hip_atomic_store(&g_grp[gi].cnt, 0u, __ATOMIC_RELAXED,
                           __HIP_MEMORY_SCOPE_AGENT);
        __hip_atomic_fetch_add(&g_root.acc, gsum, __ATOMIC_RELAXED,
                               __HIP_MEMORY_SCOPE_AGENT);
        unsigned old2 = __hip_atomic_fetch_add(&g_root.cnt, 1u,
                                               __ATOMIC_ACQ_REL,
                                               __HIP_MEMORY_SCOPE_AGENT);
        if (old2 == (NBLK / GRPBLK) - 1) {
          long long tot = __hip_atomic_load(&g_root.acc, __ATOMIC_RELAXED,
                                            __HIP_MEMORY_SCOPE_AGENT);
          out[0] = (float)((double)tot * INV_SCALE);
          __hip_atomic_store(&g_root.acc, 0ll, __ATOMIC_RELAXED,
                             __HIP_MEMORY_SCOPE_AGENT);
          __hip_atomic_store(&g_root.cnt, 0u, __ATOMIC_RELAXED,
                             __HIP_MEMORY_SCOPE_AGENT);
        }
      }
    }
  }
}

__global__ __launch_bounds__(BLK) void fused_kernel(
    const float* __restrict__ S1, const int* __restrict__ step,
    const float* __restrict__ loss, const float* __restrict__ lrs,
    const float* __restrict__ lr_sum, const float* __restrict__ lr_gap,
    const float* __restrict__ L0_p, const float* __restrict__ A_p,
    const float* __restrict__ alpha_p, const float* __restrict__ B_p,
    const float* __restrict__ C_p, const float* __restrict__ beta_p,
    const float* __restrict__ gamma_p,
    float* __restrict__ out, int T) {
  __shared__ float segm[MAXSEG][LSTRIDE];
  __shared__ __align__(16) float lc[LSTG];
  __shared__ __align__(16) float ldd[LSTG];
  __shared__ __align__(16) float lgp[LSTG];
  __shared__ float wacc[NW][GSZ];

  float beta = beta_p[0];
  float C = C_p[0], gam = gamma_p[0];
  if (beta == 0.5f)
    body<true>(S1, step, loss, lrs, lr_sum, lr_gap, L0_p, A_p, alpha_p, B_p,
               C, -0.5f, out, T, segm, lc, ldd, lgp, wacc, gam);
  else
    body<false>(S1, step, loss, lrs, lr_sum, lr_gap, L0_p, A_p, alpha_p, B_p,
                C, -beta, out, T, segm, lc, ldd, lgp, wacc, gam);
}

extern "C" void kernel_launch(void* const* d_in, const int* in_sizes, int n_in,
                              void* d_out, int out_size, void* d_ws, size_t ws_size,
                              hipStream_t stream) {
  const float* S1      = (const float*)d_in[0];
  const float* lrs     = (const float*)d_in[1];
  const float* lr_sum  = (const float*)d_in[2];
  const int*   step    = (const int*)  d_in[3];
  const float* lr_gap  = (const float*)d_in[4];
  const float* loss    = (const float*)d_in[5];
  const float* L0_p    = (const float*)d_in[6];
  const float* A_p     = (const float*)d_in[7];
  const float* alpha_p = (const float*)d_in[8];
  const float* B_p     = (const float*)d_in[9];
  const float* C_p     = (const float*)d_in[10];
  const float* beta_p  = (const float*)d_in[11];
  const float* gamma_p = (const float*)d_in[12];

  int M = in_sizes[0];
  int T = in_sizes[1];

  fused_kernel<<<M / GSZ, BLK, 0, stream>>>(
      S1, step, loss, lrs, lr_sum, lr_gap,
      L0_p, A_p, alpha_p, B_p, C_p, beta_p, gamma_p,
      (float*)d_out, T);
}

// Round 20
// 23.833 us; speedup vs baseline: 3.1897x; 1.2758x over previous
//
#include <hip/hip_runtime.h>
#include <math.h>

#define BLK 1024         // threads per block (16 waves) — occupancy for latency
#define NBLK 256         // blocks = M/GSZ (1 per CU)
#define GSZ 32           // checkpoints per block
#define HSZ 4            // checkpoints per group  [R20: 8->4 -> fits 64 VGPR]
#define GTH 128          // threads per group (2 waves), 8 groups
#define NW 16            // waves per block
#define SEGW 256         // k-elements per moment segment
#define SEGSH 8          // log2(SEGW)
#define NSEG_NEAR 3      // far/near boundary: 3*256 = 768 steps exact
#define NDEG 6           // expansion degree (moments 0..6)
#define LSTRIDE 9        // LDS floats per segment record (odd: conflict-free)
#define MAXSEG 64        // 16384/256
#define LSTG 2048        // staged near-field elements
#define GRPBLK 16        // blocks per atomic group
#define SCALEF 1.125899906842624e15f   // 2^50 fixed-point scale
#define INV_SCALE (1.0 / 1.125899906842624e15)

#if __has_builtin(__builtin_amdgcn_rsqf)
#define RSQF(x) __builtin_amdgcn_rsqf(x)
#else
#define RSQF(x) (1.0f / sqrtf(x))
#endif
#if __has_builtin(__builtin_amdgcn_rcpf)
#define RCPF(x) __builtin_amdgcn_rcpf(x)
#else
#define RCPF(x) (1.0f / (x))
#endif

__device__ __forceinline__ float fast_pow(float x, float e) {
  return __expf(e * __logf(x));  // x>0; ~1e-6 rel err vs 0.176 abs budget
}

__device__ __forceinline__ float bsum64(float v) {
#pragma unroll
  for (int m = 1; m < 64; m <<= 1) v += __shfl_xor(v, m, 64);
  return v;
}

// Atomic tree slots, each on its OWN 128B line (R15/R16 lesson).
// Zero-init at load; last users reset -> clean for every replay (proven
// across R15-R19 replays).
struct __align__(128) Slot { long long acc; unsigned cnt; };
__device__ Slot g_grp[NBLK / GRPBLK];
__device__ Slot g_root;

// ---------------------------------------------------------------------------
// R17 math, 1024 threads (16 waves: latency hiding per R19) with HSZ=4
// per-group state (no spill per R18's VGPR-64 diagnosis: WRITE_SIZE 49MB
// was scratch traffic from HSZ=8's ~100-reg working set).
// ---------------------------------------------------------------------------
template <bool USE_RSQ>
__device__ __forceinline__ void body(
    const float* __restrict__ S1, const int* __restrict__ step,
    const float* __restrict__ loss, const float* __restrict__ lrs,
    const float* __restrict__ lr_sum, const float* __restrict__ lr_gap,
    const float* __restrict__ L0_p, const float* __restrict__ A_p,
    const float* __restrict__ alpha_p, const float* __restrict__ B_p,
    float C, float nb, float* __restrict__ out, int T,
    float (&segm)[MAXSEG][LSTRIDE], float (&lc)[LSTG], float (&ldd)[LSTG],
    float (&lgp)[LSTG], float (&wacc)[NW][GSZ], float gam) {
  int tid = threadIdx.x, bid = blockIdx.x;
  int lane = tid & 63, wid = tid >> 6;
  int grp = tid >> 7;          // 8 groups x 2 waves
  int jb = grp * HSZ;
  int htid = tid & (GTH - 1);  // 0..127 within group

  int mbase = bid * GSZ;

  // ---- block-wide scan (broadcast loads) ----
  int nsegmax = 0, minlo = 1 << 30, utop = 0;
#pragma unroll
  for (int jj = 0; jj < GSZ; ++jj) {
    int s = step[mbase + jj];
    int ks = max(0, (s >> SEGSH) - NSEG_NEAR);
    nsegmax = max(nsegmax, ks);
    minlo = min(minlo, ks << SEGSH);
    utop = max(utop, s);
  }
  int ubase = minlo;
  int ucnt = min(LSTG, (utop - ubase + 7) & ~3);

  // ---- prep: per-wave segment moments (4 k's per lane, unrolled ILP) ----
  for (int seg = wid; seg < nsegmax; seg += NW) {
    float dk[4], wk[4];
#pragma unroll
    for (int e = 0; e < 4; ++e) {
      int k = seg * SEGW + lane * 4 + e;   // <= 60*256+255 < T always
      if (k == 0) {
        dk[e] = 0.0f; wk[e] = 0.0f;        // k=0 contributes nothing
      } else {
        float lg = __logf(lrs[k]);
        float c  = C * __expf(-gam * lg);  // C * lrs^-gamma
        dk[e] = RCPF(c) - lr_sum[k - 1];
        wk[e] = USE_RSQ ? (lr_gap[k] * RSQF(c))
                        : (lr_gap[k] * fast_pow(c, nb));
      }
    }
    float d0 = bsum64(dk[0] + dk[1] + dk[2] + dk[3]) * (1.0f / 256.0f);
    float e0 = dk[0] - d0, e1 = dk[1] - d0, e2 = dk[2] - d0, e3 = dk[3] - d0;
    float p0 = wk[0], p1 = wk[1], p2 = wk[2], p3 = wk[3];
    float b = 1.0f;                        // binom(nb, n) recurrence
#pragma unroll
    for (int n = 0; n <= NDEG; ++n) {      // unrolled: 7 bsum chains overlap
      float v = bsum64(p0 + p1 + p2 + p3);
      if (lane == 0) segm[seg][1 + n] = b * v;
      p0 *= e0; p1 *= e1; p2 *= e2; p3 *= e3;
      b *= (nb - (float)n) / (float)(n + 1);
    }
    if (lane == 0) segm[seg][0] = d0;
  }

  // ---- stage near-field (c, dd, g) once per block into LDS ----
  for (int i = tid; i < ucnt; i += BLK) {
    int k = ubase + i;
    if (k == 0 || k >= T) {
      lc[i] = 0.0f; ldd[i] = 1.0f; lgp[i] = 0.0f;
    } else {
      float lg = __logf(lrs[k]);
      float c  = C * __expf(-gam * lg);
      lc[i] = c;
      ldd[i] = fmaf(-c, lr_sum[k - 1], 1.0f);
      lgp[i] = lr_gap[k];
    }
  }
  __syncthreads();

  // ---- per-group checkpoint state (4-wide arrays: ~16 regs, no spill) ----
  float Ss[HSZ], acc[HSZ]; int sv[HSZ], ksg[HSZ];
  int lo_g = 1 << 30, smax_g = 0, nsegh = 0;
#pragma unroll
  for (int jj = 0; jj < HSZ; ++jj) {
    int m = mbase + jb + jj;
    Ss[jj] = S1[m];
    int s = step[m];
    sv[jj] = s;
    int kg = max(0, (s >> SEGSH) - NSEG_NEAR);
    ksg[jj] = kg;
    acc[jj] = 0.0f;
    lo_g = min(lo_g, kg << SEGSH);
    smax_g = max(smax_g, s);
    nsegh = max(nsegh, kg);
  }

  // ---- far field: thread htid evaluates segment htid (nsegh <= 60 < 128) ----
  if (htid < nsegh) {
    float d0 = segm[htid][0];
    float mm[NDEG + 1];
#pragma unroll
    for (int n = 0; n <= NDEG; ++n) mm[n] = segm[htid][1 + n];
#pragma unroll
    for (int jj = 0; jj < HSZ; ++jj) {
      float s_ = Ss[jj] + d0;
      float r = RCPF(s_);
      float tb = USE_RSQ ? RSQF(s_) : fast_pow(s_, nb);
      float h = mm[NDEG];
#pragma unroll
      for (int n = NDEG - 1; n >= 0; --n) h = fmaf(h, r, mm[n]);
      float contrib = tb * h;
      acc[jj] += (htid < ksg[jj]) ? contrib : 0.0f;  // select AFTER compute
    }
  }

  // ---- near field: masked sweep from staged LDS (float4) ----
  for (int kb = lo_g + htid * 4; kb <= smax_g; kb += GTH * 4) {
    int idx = kb - ubase;  // multiple of 4 (256-aligned bases)
    float4 c4, d4, g4;
    if (idx < LSTG) {
      c4 = *(const float4*)&lc[idx];
      d4 = *(const float4*)&ldd[idx];
      g4 = *(const float4*)&lgp[idx];
    } else {  // rare fallback: span exceeded LSTG — recompute
      float ce_[4], de_[4], ge_[4];
#pragma unroll
      for (int e = 0; e < 4; ++e) {
        int k = kb + e;
        if (k < 1 || k >= T) { ce_[e]=0.0f; de_[e]=1.0f; ge_[e]=0.0f; }
        else {
          float lg = __logf(lrs[k]);
          float c  = C * __expf(-gam * lg);
          ce_[e] = c; de_[e] = fmaf(-c, lr_sum[k - 1], 1.0f);
          ge_[e] = lr_gap[k];
        }
      }
      c4 = {ce_[0], ce_[1], ce_[2], ce_[3]};
      d4 = {de_[0], de_[1], de_[2], de_[3]};
      g4 = {ge_[0], ge_[1], ge_[2], ge_[3]};
    }
    const float ce[4] = {c4.x, c4.y, c4.z, c4.w};
    const float de[4] = {d4.x, d4.y, d4.z, d4.w};
    const float ge[4] = {g4.x, g4.y, g4.z, g4.w};
#pragma unroll
    for (int e = 0; e < 4; ++e) {
#pragma unroll
      for (int jj = 0; jj < HSZ; ++jj) {
        float inner = fmaf(ce[e], Ss[jj], de[e]);  // may be <=0 if masked
        float p = USE_RSQ ? RSQF(inner) : __expf(nb * __logf(inner));
        unsigned off = (unsigned)(kb + e - (ksg[jj] << SEGSH));
        unsigned rngj = (unsigned)(sv[jj] - (ksg[jj] << SEGSH));
        float pm = (off <= rngj) ? p : 0.0f;  // select AFTER p (NaN-safe)
        acc[jj] = fmaf(ge[e], pm, acc[jj]);
      }
    }
  }

  // ---- block reduce: wave shuffle, then across the 2 group-waves via LDS ----
#pragma unroll
  for (int jj = 0; jj < HSZ; ++jj) {
    float v = acc[jj];
#pragma unroll
    for (int off = 32; off; off >>= 1) v += __shfl_down(v, off, 64);
    if (lane == 0) wacc[wid][jb + jj] = v;
  }
  __syncthreads();

  // ---- epilogue + tree-reduced deterministic global sum (R16, proven) ----
  long long ll = 0;
  if (tid < GSZ) {
    int j = tid;
    int m = mbase + j;
    int w0 = (j >> 2) * 2;   // 2 waves per 4-checkpoint group
    float sgp = wacc[w0][j] + wacc[w0 + 1][j];
    int s = step[m];
    float Ssum = S1[m];
    float LD = (lrs[0] - lrs[s]) - sgp;   // telescoped gap sum
    float pred = L0_p[0] + A_p[0] * fast_pow(Ssum, -alpha_p[0]) + B_p[0] * LD;
    pred = fmaxf(pred, 1e-10f);
    float r = __logf(loss[m]) - __logf(pred);
    float a = fabsf(r);
    const float dlt = 0.001f;
    float hubv = (a <= dlt) ? (0.5f * r * r) : (dlt * (a - 0.5f * dlt));
    ll = (long long)(hubv * SCALEF + 0.5f);  // hubv >= 0
  }
  if (wid == 0) {
#pragma unroll
    for (int off = 16; off; off >>= 1) ll += __shfl_down(ll, off, 64);
    if (lane == 0) {
      int gi = bid / GRPBLK;
      __hip_atomic_fetch_add(&g_grp[gi].acc, ll, __ATOMIC_RELAXED,
                             __HIP_MEMORY_SCOPE_AGENT);
      unsigned old = __hip_atomic_fetch_add(&g_grp[gi].cnt, 1u,
                                            __ATOMIC_ACQ_REL,
                                            __HIP_MEMORY_SCOPE_AGENT);
      if (old == GRPBLK - 1) {
        long long gsum = __hip_atomic_load(&g_grp[gi].acc, __ATOMIC_RELAXED,
                                           __HIP_MEMORY_SCOPE_AGENT);
        __hip_atomic_store(&g_grp[gi].acc, 0ll, __ATOMIC_RELAXED,
                           __HIP_MEMORY_SCOPE_AGENT);
        __hip_atomic_store(&g_grp[gi].cnt, 0u, __ATOMIC_RELAXED,
                           __HIP_MEMORY_SCOPE_AGENT);
        __hip_atomic_fetch_add(&g_root.acc, gsum, __ATOMIC_RELAXED,
                               __HIP_MEMORY_SCOPE_AGENT);
        unsigned old2 = __hip_atomic_fetch_add(&g_root.cnt, 1u,
                                               __ATOMIC_ACQ_REL,
                                               __HIP_MEMORY_SCOPE_AGENT);
        if (old2 == (NBLK / GRPBLK) - 1) {
          long long tot = __hip_atomic_load(&g_root.acc, __ATOMIC_RELAXED,
                                            __HIP_MEMORY_SCOPE_AGENT);
          out[0] = (float)((double)tot * INV_SCALE);
          __hip_atomic_store(&g_root.acc, 0ll, __ATOMIC_RELAXED,
                             __HIP_MEMORY_SCOPE_AGENT);
          __hip_atomic_store(&g_root.cnt, 0u, __ATOMIC_RELAXED,
                             __HIP_MEMORY_SCOPE_AGENT);
        }
      }
    }
  }
}

__global__ __launch_bounds__(BLK) void fused_kernel(
    const float* __restrict__ S1, const int* __restrict__ step,
    const float* __restrict__ loss, const float* __restrict__ lrs,
    const float* __restrict__ lr_sum, const float* __restrict__ lr_gap,
    const float* __restrict__ L0_p, const float* __restrict__ A_p,
    const float* __restrict__ alpha_p, const float* __restrict__ B_p,
    const float* __restrict__ C_p, const float* __restrict__ beta_p,
    const float* __restrict__ gamma_p,
    float* __restrict__ out, int T) {
  __shared__ float segm[MAXSEG][LSTRIDE];
  __shared__ __align__(16) float lc[LSTG];
  __shared__ __align__(16) float ldd[LSTG];
  __shared__ __align__(16) float lgp[LSTG];
  __shared__ float wacc[NW][GSZ];

  float beta = beta_p[0];
  float C = C_p[0], gam = gamma_p[0];
  if (beta == 0.5f)
    body<true>(S1, step, loss, lrs, lr_sum, lr_gap, L0_p, A_p, alpha_p, B_p,
               C, -0.5f, out, T, segm, lc, ldd, lgp, wacc, gam);
  else
    body<false>(S1, step, loss, lrs, lr_sum, lr_gap, L0_p, A_p, alpha_p, B_p,
                C, -beta, out, T, segm, lc, ldd, lgp, wacc, gam);
}

extern "C" void kernel_launch(void* const* d_in, const int* in_sizes, int n_in,
                              void* d_out, int out_size, void* d_ws, size_t ws_size,
                              hipStream_t stream) {
  const float* S1      = (const float*)d_in[0];
  const float* lrs     = (const float*)d_in[1];
  const float* lr_sum  = (const float*)d_in[2];
  const int*   step    = (const int*)  d_in[3];
  const float* lr_gap  = (const float*)d_in[4];
  const float* loss    = (const float*)d_in[5];
  const float* L0_p    = (const float*)d_in[6];
  const float* A_p     = (const float*)d_in[7];
  const float* alpha_p = (const float*)d_in[8];
  const float* B_p     = (const float*)d_in[9];
  const float* C_p     = (const float*)d_in[10];
  const float* beta_p  = (const float*)d_in[11];
  const float* gamma_p = (const float*)d_in[12];

  int M = in_sizes[0];
  int T = in_sizes[1];

  fused_kernel<<<M / GSZ, BLK, 0, stream>>>(
      S1, step, loss, lrs, lr_sum, lr_gap,
      L0_p, A_p, alpha_p, B_p, C_p, beta_p, gamma_p,
      (float*)d_out, T);
}